// Round 4
// baseline (2273.683 us; speedup 1.0000x reference)
//
#include <hip/hip_runtime.h>

#define T_TOK 8192
#define DDIM 1024
#define IDIM 2048
#define NEXP 8

typedef short bf16x8 __attribute__((ext_vector_type(8)));
typedef float f32x4 __attribute__((ext_vector_type(4)));

__device__ __forceinline__ unsigned short f2bf(float f) {
  union { float f; unsigned int u; } v; v.f = f;
  unsigned int r = v.u + 0x7fffu + ((v.u >> 16) & 1u);
  return (unsigned short)(r >> 16);
}

// raw barrier: does NOT drain vmcnt (unlike __syncthreads) -- prefetch loads stay in flight
__device__ __forceinline__ void barrier_raw() {
  asm volatile("s_barrier" ::: "memory");
}
__device__ __forceinline__ void lds_fence() {
  asm volatile("s_waitcnt lgkmcnt(0)" ::: "memory");
}

// ---------------- x -> bf16 ----------------
__global__ __launch_bounds__(256) void convert_kernel(const float* __restrict__ x,
                                                      ushort* __restrict__ xb, int n4) {
  int i = blockIdx.x * 256 + threadIdx.x;
  if (i >= n4) return;
  float4 v = ((const float4*)x)[i];
  ushort4 o;
  o.x = f2bf(v.x); o.y = f2bf(v.y); o.z = f2bf(v.z); o.w = f2bf(v.w);
  ((ushort4*)xb)[i] = o;
}

// ---------------- transpose + convert via LDS: src[e][R][C] f32 -> dst[e][C'][R] bf16 ----------------
__global__ __launch_bounds__(256) void tconv_kernel(
    const float* __restrict__ src, ushort* __restrict__ dst, int R, int C,
    int sel, int interleave, size_t srcEStride, size_t dstEStride) {
  __shared__ ushort lt[64 * 72];
  const int e = blockIdx.z;
  const float* s = src + (size_t)e * srcEStride;
  ushort* d = dst + (size_t)e * dstEStride;
  const int c0 = blockIdx.x * 64, r0 = blockIdx.y * 64;
  const int t = threadIdx.x;
  const int tr = t >> 2;
  const int tc = (t & 3) * 16;
  const float* sp = s + (size_t)(r0 + tr) * C + c0 + tc;
  float4 v0 = ((const float4*)sp)[0];
  float4 v1 = ((const float4*)sp)[1];
  float4 v2 = ((const float4*)sp)[2];
  float4 v3 = ((const float4*)sp)[3];
#pragma unroll
  for (int j = 0; j < 4; ++j) lt[(tc + j) * 72 + tr]      = f2bf(((const float*)&v0)[j]);
#pragma unroll
  for (int j = 0; j < 4; ++j) lt[(tc + 4 + j) * 72 + tr]  = f2bf(((const float*)&v1)[j]);
#pragma unroll
  for (int j = 0; j < 4; ++j) lt[(tc + 8 + j) * 72 + tr]  = f2bf(((const float*)&v2)[j]);
#pragma unroll
  for (int j = 0; j < 4; ++j) lt[(tc + 12 + j) * 72 + tr] = f2bf(((const float*)&v3)[j]);
  __syncthreads();
  const int cr = t >> 2;
  const int seg = (t & 3) * 16;
  const int ci = c0 + cr;
  const int drow = interleave ? ((ci >> 6) * 128 + sel * 64 + (ci & 63)) : ci;
  uint4 o0 = *(const uint4*)&lt[cr * 72 + seg];
  uint4 o1 = *(const uint4*)&lt[cr * 72 + seg + 8];
  ushort* dp = d + (size_t)drow * R + r0 + seg;
  *(uint4*)dp = o0;
  *(uint4*)(dp + 8) = o1;
}

// ---------------- router: top-2 + expert lists ----------------
__global__ __launch_bounds__(256) void router_kernel(
    const float* __restrict__ x, const float* __restrict__ rw, const float* __restrict__ rb,
    int* __restrict__ cnt, int* __restrict__ lists, float* __restrict__ wts) {
  const int token = blockIdx.x * 4 + (threadIdx.x >> 6);
  const int lane = threadIdx.x & 63;
  float acc[NEXP];
#pragma unroll
  for (int e = 0; e < NEXP; ++e) acc[e] = 0.f;
  const float* xr = x + (size_t)token * DDIM;
#pragma unroll
  for (int j = 0; j < DDIM / 64; ++j) {
    int d = j * 64 + lane;
    float xv = xr[d];
    const float4* w = (const float4*)(rw + d * NEXP);
    float4 w0 = w[0], w1 = w[1];
    acc[0] += xv * w0.x; acc[1] += xv * w0.y; acc[2] += xv * w0.z; acc[3] += xv * w0.w;
    acc[4] += xv * w1.x; acc[5] += xv * w1.y; acc[6] += xv * w1.z; acc[7] += xv * w1.w;
  }
#pragma unroll
  for (int e = 0; e < NEXP; ++e) {
    float v = acc[e];
    for (int off = 32; off > 0; off >>= 1) v += __shfl_xor(v, off, 64);
    acc[e] = v;
  }
  if (lane == 0) {
    float l[NEXP];
#pragma unroll
    for (int e = 0; e < NEXP; ++e) l[e] = acc[e] + rb[e];
    int i0 = 0; float b0 = l[0];
#pragma unroll
    for (int e = 1; e < NEXP; ++e) if (l[e] > b0) { b0 = l[e]; i0 = e; }
    int i1 = -1; float b1 = -3.0e38f;
#pragma unroll
    for (int e = 0; e < NEXP; ++e) if (e != i0 && l[e] > b1) { b1 = l[e]; i1 = e; }
    float e1 = expf(b1 - b0);
    float inv = 1.f / (1.f + e1);
    wts[token * 2 + 0] = inv;
    wts[token * 2 + 1] = e1 * inv;
    int s0 = atomicAdd(&cnt[i0], 1);
    lists[i0 * T_TOK + s0] = token * 2;
    int s1 = atomicAdd(&cnt[i1], 1);
    lists[i1 * T_TOK + s1] = token * 2 + 1;
  }
}

// ---------------- GEMM1: fused gate/up, reg-prefetch pipeline, 128m x 64 pairs, BK=64 ----------------
// Each wave: 32 m-rows x 64 pair-cols, accumulates BOTH gate and up (no epilogue exchange).
__global__ __launch_bounds__(256, 3) void gemm1_kernel(
    const ushort* __restrict__ xb, const ushort* __restrict__ wcat,
    const float* __restrict__ gate_b, const float* __restrict__ up_b,
    const int* __restrict__ lists, const int* __restrict__ cnt,
    ushort* __restrict__ hbuf) {
  const int e = blockIdx.z;
  const int ce = cnt[e];
  const int m0 = blockIdx.x * 128;
  if (m0 >= ce) return;
  const int by = blockIdx.y;  // 0..31 -> pair cols 64*by..+63

  __shared__ __align__(16) ushort smem[16384];  // As[128][64] | Bs[128][64], 32 KB
  ushort* As = smem;
  ushort* Bs = smem + 8192;

  const int tid = threadIdx.x;
  const int w = tid >> 6, lane = tid & 63;
  const int fm = lane & 15, fq = lane >> 4;
  const int lr = lane >> 3;                  // 0..7
  const int lchunk = ((lane & 7) ^ lr) * 8;  // swizzled global chunk
  const int wchunk = (lane & 7) * 8;         // LDS chunk (matches lane-linear layout)

  const int* listE = lists + e * T_TOK;
  const ushort* wcatE = wcat + (size_t)e * 4096 * 1024;
  const ushort* aG[4]; const ushort* bG[4];
  ushort* aLw[4]; ushort* bLw[4];
#pragma unroll
  for (int j = 0; j < 4; ++j) {
    int rl = 32 * w + 8 * j + lr;
    int slot = m0 + rl;
    int packed = listE[slot < ce ? slot : 0];
    aG[j] = xb + (size_t)(packed >> 1) * DDIM + lchunk;
    bG[j] = wcatE + (size_t)(128 * by + rl) * DDIM + lchunk;
    aLw[j] = &As[(32 * w + 8 * j + lr) * 64 + wchunk];
    bLw[j] = &Bs[(32 * w + 8 * j + lr) * 64 + wchunk];
  }

  f32x4 accg[2][4], accu[2][4];
  const f32x4 zero4 = {0.f, 0.f, 0.f, 0.f};
#pragma unroll
  for (int i = 0; i < 2; ++i)
#pragma unroll
    for (int j = 0; j < 4; ++j) { accg[i][j] = zero4; accu[i][j] = zero4; }

  uint4 pfa[4], pfb[4];
#pragma unroll
  for (int j = 0; j < 4; ++j) { pfa[j] = *(const uint4*)aG[j]; pfb[j] = *(const uint4*)bG[j]; }

#pragma unroll 1
  for (int kt = 0; kt < DDIM / 64; ++kt) {
    barrier_raw();  // readers of tile kt-1 done; LDS free
#pragma unroll
    for (int j = 0; j < 4; ++j) { *(uint4*)aLw[j] = pfa[j]; *(uint4*)bLw[j] = pfb[j]; }
    lds_fence();
    barrier_raw();  // tile kt visible to all waves
    if (kt + 1 < DDIM / 64) {
#pragma unroll
      for (int j = 0; j < 4; ++j) {
        pfa[j] = *(const uint4*)(aG[j] + (kt + 1) * 64);
        pfb[j] = *(const uint4*)(bG[j] + (kt + 1) * 64);
      }
    }
#pragma unroll
    for (int ks = 0; ks < 2; ++ks) {
      const int sw = ((ks * 4 + fq) ^ (fm & 7)) * 8;
      bf16x8 af[2], bg[4], bu[4];
#pragma unroll
      for (int mf = 0; mf < 2; ++mf)
        af[mf] = *(const bf16x8*)&As[(32 * w + 16 * mf + fm) * 64 + sw];
#pragma unroll
      for (int nf = 0; nf < 4; ++nf) {
        bg[nf] = *(const bf16x8*)&Bs[(16 * nf + fm) * 64 + sw];
        bu[nf] = *(const bf16x8*)&Bs[(64 + 16 * nf + fm) * 64 + sw];
      }
#pragma unroll
      for (int mf = 0; mf < 2; ++mf)
#pragma unroll
        for (int nf = 0; nf < 4; ++nf) {
          accg[mf][nf] = __builtin_amdgcn_mfma_f32_16x16x32_bf16(af[mf], bg[nf], accg[mf][nf], 0, 0, 0);
          accu[mf][nf] = __builtin_amdgcn_mfma_f32_16x16x32_bf16(af[mf], bu[nf], accu[mf][nf], 0, 0, 0);
        }
    }
  }

  // epilogue: g and u co-resident per thread -> fuse directly, no LDS exchange
#pragma unroll
  for (int mf = 0; mf < 2; ++mf) {
#pragma unroll
    for (int r = 0; r < 4; ++r) {
      const int row = 32 * w + 16 * mf + 4 * fq + r;
      if (m0 + row < ce) {
        const int packed = listE[m0 + row];
        ushort* hrow = hbuf + (size_t)packed * IDIM + 64 * by;
#pragma unroll
        for (int nf = 0; nf < 4; ++nf) {
          const int col = 16 * nf + fm;
          float g = accg[mf][nf][r] + gate_b[e * IDIM + 64 * by + col];
          float u = accu[mf][nf][r] + up_b[e * IDIM + 64 * by + col];
          float h = g * (1.f / (1.f + __expf(-g))) * u;
          hrow[col] = f2bf(h);
        }
      }
    }
  }
}

// ---------------- GEMM2: out += w * (h @ down_w + down_b), reg-prefetch pipeline ----------------
__global__ __launch_bounds__(256, 3) void gemm2_kernel(
    const ushort* __restrict__ hbuf, const ushort* __restrict__ downT,
    const float* __restrict__ down_b,
    const int* __restrict__ lists, const int* __restrict__ cnt,
    const float* __restrict__ wts, float* __restrict__ out) {
  const int e = blockIdx.z;
  const int ce = cnt[e];
  const int m0 = blockIdx.x * 128;
  if (m0 >= ce) return;
  const int by = blockIdx.y;  // 0..7 -> out cols 128*by..

  __shared__ __align__(16) ushort smem[16384];
  ushort* As = smem;
  ushort* Bs = smem + 8192;

  const int tid = threadIdx.x;
  const int w = tid >> 6, lane = tid & 63;
  const int fm = lane & 15, fq = lane >> 4;
  const int waveM = w >> 1, waveN = w & 1;
  const int lr = lane >> 3;
  const int lchunk = ((lane & 7) ^ lr) * 8;
  const int wchunk = (lane & 7) * 8;

  const int* listE = lists + e * T_TOK;
  const ushort* downE = downT + (size_t)e * DDIM * IDIM;
  const ushort* aG[4]; const ushort* bG[4];
  ushort* aLw[4]; ushort* bLw[4];
#pragma unroll
  for (int j = 0; j < 4; ++j) {
    int rl = 32 * w + 8 * j + lr;
    int slot = m0 + rl;
    int packed = listE[slot < ce ? slot : 0];
    aG[j] = hbuf + (size_t)packed * IDIM + lchunk;
    bG[j] = downE + (size_t)(128 * by + rl) * IDIM + lchunk;
    aLw[j] = &As[(32 * w + 8 * j + lr) * 64 + wchunk];
    bLw[j] = &Bs[(32 * w + 8 * j + lr) * 64 + wchunk];
  }

  f32x4 acc[4][4];
  const f32x4 zero4 = {0.f, 0.f, 0.f, 0.f};
#pragma unroll
  for (int i = 0; i < 4; ++i)
#pragma unroll
    for (int j = 0; j < 4; ++j) acc[i][j] = zero4;

  uint4 pfa[4], pfb[4];
#pragma unroll
  for (int j = 0; j < 4; ++j) { pfa[j] = *(const uint4*)aG[j]; pfb[j] = *(const uint4*)bG[j]; }

#pragma unroll 1
  for (int kt = 0; kt < IDIM / 64; ++kt) {
    barrier_raw();
#pragma unroll
    for (int j = 0; j < 4; ++j) { *(uint4*)aLw[j] = pfa[j]; *(uint4*)bLw[j] = pfb[j]; }
    lds_fence();
    barrier_raw();
    if (kt + 1 < IDIM / 64) {
#pragma unroll
      for (int j = 0; j < 4; ++j) {
        pfa[j] = *(const uint4*)(aG[j] + (kt + 1) * 64);
        pfb[j] = *(const uint4*)(bG[j] + (kt + 1) * 64);
      }
    }
#pragma unroll
    for (int ks = 0; ks < 2; ++ks) {
      const int sw = ((ks * 4 + fq) ^ (fm & 7)) * 8;
      bf16x8 af[4], bfr[4];
#pragma unroll
      for (int mf = 0; mf < 4; ++mf)
        af[mf] = *(const bf16x8*)&As[(64 * waveM + 16 * mf + fm) * 64 + sw];
#pragma unroll
      for (int nf = 0; nf < 4; ++nf)
        bfr[nf] = *(const bf16x8*)&Bs[(64 * waveN + 16 * nf + fm) * 64 + sw];
#pragma unroll
      for (int mf = 0; mf < 4; ++mf)
#pragma unroll
        for (int nf = 0; nf < 4; ++nf)
          acc[mf][nf] = __builtin_amdgcn_mfma_f32_16x16x32_bf16(af[mf], bfr[nf], acc[mf][nf], 0, 0, 0);
    }
  }

#pragma unroll
  for (int mf = 0; mf < 4; ++mf) {
#pragma unroll
    for (int r = 0; r < 4; ++r) {
      const int row = 64 * waveM + 16 * mf + 4 * fq + r;
      if (m0 + row < ce) {
        const int packed = listE[m0 + row];
        const float wt = wts[packed];
        const int token = packed >> 1;
#pragma unroll
        for (int nf = 0; nf < 4; ++nf) {
          const int col = 128 * by + 64 * waveN + 16 * nf + fm;
          atomicAdd(&out[(size_t)token * DDIM + col], wt * (acc[mf][nf][r] + down_b[e * DDIM + col]));
        }
      }
    }
  }
}

extern "C" void kernel_launch(void* const* d_in, const int* in_sizes, int n_in,
                              void* d_out, int out_size, void* d_ws, size_t ws_size,
                              hipStream_t stream) {
  const float* x = (const float*)d_in[0];
  const float* rw = (const float*)d_in[1];
  const float* rb = (const float*)d_in[2];
  const float* gw = (const float*)d_in[3];
  const float* gb = (const float*)d_in[4];
  const float* uw = (const float*)d_in[5];
  const float* ub = (const float*)d_in[6];
  const float* dw = (const float*)d_in[7];
  const float* db = (const float*)d_in[8];
  float* out = (float*)d_out;

  char* ws = (char*)d_ws;
  ushort* xb    = (ushort*)(ws);                              // 16 MB
  ushort* hbuf  = (ushort*)(ws + (16ull << 20));              // 64 MB
  ushort* wcat  = (ushort*)(ws + (80ull << 20));              // 64 MB
  ushort* downT = (ushort*)(ws + (144ull << 20));             // 32 MB
  float*  wts   = (float*) (ws + (176ull << 20));             // 64 KB
  int*    lists = (int*)   (ws + (176ull << 20) + 65536);     // 256 KB
  int*    cnt   = (int*)   (ws + (176ull << 20) + 65536 + 262144);

  hipMemsetAsync(cnt, 0, NEXP * sizeof(int), stream);
  hipMemsetAsync(out, 0, (size_t)out_size * sizeof(float), stream);

  convert_kernel<<<(T_TOK * DDIM / 4 + 255) / 256, 256, 0, stream>>>(x, xb, T_TOK * DDIM / 4);
  router_kernel<<<T_TOK / 4, 256, 0, stream>>>(x, rw, rb, cnt, lists, wts);
  tconv_kernel<<<dim3(IDIM / 64, DDIM / 64, NEXP), 256, 0, stream>>>(
      gw, wcat, DDIM, IDIM, 0, 1, (size_t)DDIM * IDIM, (size_t)2 * IDIM * DDIM);
  tconv_kernel<<<dim3(IDIM / 64, DDIM / 64, NEXP), 256, 0, stream>>>(
      uw, wcat, DDIM, IDIM, 1, 1, (size_t)DDIM * IDIM, (size_t)2 * IDIM * DDIM);
  tconv_kernel<<<dim3(DDIM / 64, IDIM / 64, NEXP), 256, 0, stream>>>(
      dw, downT, IDIM, DDIM, 0, 0, (size_t)IDIM * DDIM, (size_t)DDIM * IDIM);

  gemm1_kernel<<<dim3(T_TOK / 128, IDIM / 64, NEXP), 256, 0, stream>>>(
      xb, wcat, gb, ub, lists, cnt, hbuf);
  gemm2_kernel<<<dim3(T_TOK / 128, DDIM / 128, NEXP), 256, 0, stream>>>(
      hbuf, downT, db, lists, cnt, wts, out);
}

// Round 5
// 843.244 us; speedup vs baseline: 2.6964x; 2.6964x over previous
//
#include <hip/hip_runtime.h>

#define T_TOK 8192
#define DDIM 1024
#define IDIM 2048
#define NEXP 8
#define STAGE 16384

typedef short bf16x8 __attribute__((ext_vector_type(8)));
typedef float f32x4 __attribute__((ext_vector_type(4)));

__device__ __forceinline__ unsigned short f2bf(float f) {
  union { float f; unsigned int u; } v; v.f = f;
  unsigned int r = v.u + 0x7fffu + ((v.u >> 16) & 1u);
  return (unsigned short)(r >> 16);
}
__device__ __forceinline__ float bf2f(unsigned short u) {
  union { unsigned int u; float f; } v; v.u = (unsigned int)u << 16;
  return v.f;
}

typedef const __attribute__((address_space(1))) void* gas_t;
typedef __attribute__((address_space(3))) void* las_t;
__device__ __forceinline__ void async_copy16(void* lds, const void* g) {
  __builtin_amdgcn_global_load_lds((gas_t)g, (las_t)lds, 16, 0, 0);
}

// ---------------- x -> bf16 ----------------
__global__ __launch_bounds__(256) void convert_kernel(const float* __restrict__ x,
                                                      ushort* __restrict__ xb, int n4) {
  int i = blockIdx.x * 256 + threadIdx.x;
  if (i >= n4) return;
  float4 v = ((const float4*)x)[i];
  ushort4 o;
  o.x = f2bf(v.x); o.y = f2bf(v.y); o.z = f2bf(v.z); o.w = f2bf(v.w);
  ((ushort4*)xb)[i] = o;
}

// ---------------- transpose + convert via LDS: src[e][R][C] f32 -> dst[e][C'][R] bf16 ----------------
__global__ __launch_bounds__(256) void tconv_kernel(
    const float* __restrict__ src, ushort* __restrict__ dst, int R, int C,
    int sel, int interleave, size_t srcEStride, size_t dstEStride) {
  __shared__ ushort lt[64 * 72];
  const int e = blockIdx.z;
  const float* s = src + (size_t)e * srcEStride;
  ushort* d = dst + (size_t)e * dstEStride;
  const int c0 = blockIdx.x * 64, r0 = blockIdx.y * 64;
  const int t = threadIdx.x;
  const int tr = t >> 2;
  const int tc = (t & 3) * 16;
  const float* sp = s + (size_t)(r0 + tr) * C + c0 + tc;
  float4 v0 = ((const float4*)sp)[0];
  float4 v1 = ((const float4*)sp)[1];
  float4 v2 = ((const float4*)sp)[2];
  float4 v3 = ((const float4*)sp)[3];
#pragma unroll
  for (int j = 0; j < 4; ++j) lt[(tc + j) * 72 + tr]      = f2bf(((const float*)&v0)[j]);
#pragma unroll
  for (int j = 0; j < 4; ++j) lt[(tc + 4 + j) * 72 + tr]  = f2bf(((const float*)&v1)[j]);
#pragma unroll
  for (int j = 0; j < 4; ++j) lt[(tc + 8 + j) * 72 + tr]  = f2bf(((const float*)&v2)[j]);
#pragma unroll
  for (int j = 0; j < 4; ++j) lt[(tc + 12 + j) * 72 + tr] = f2bf(((const float*)&v3)[j]);
  __syncthreads();
  const int cr = t >> 2;
  const int seg = (t & 3) * 16;
  const int ci = c0 + cr;
  const int drow = interleave ? ((ci >> 6) * 128 + sel * 64 + (ci & 63)) : ci;
  uint4 o0 = *(const uint4*)&lt[cr * 72 + seg];
  uint4 o1 = *(const uint4*)&lt[cr * 72 + seg + 8];
  ushort* dp = d + (size_t)drow * R + r0 + seg;
  *(uint4*)dp = o0;
  *(uint4*)(dp + 8) = o1;
}

// ---------------- router: top-2 + expert lists ----------------
__global__ __launch_bounds__(256) void router_kernel(
    const float* __restrict__ x, const float* __restrict__ rw, const float* __restrict__ rb,
    int* __restrict__ cnt, int* __restrict__ lists, float* __restrict__ wts,
    int* __restrict__ pexp) {
  const int token = blockIdx.x * 4 + (threadIdx.x >> 6);
  const int lane = threadIdx.x & 63;
  float acc[NEXP];
#pragma unroll
  for (int e = 0; e < NEXP; ++e) acc[e] = 0.f;
  const float* xr = x + (size_t)token * DDIM;
#pragma unroll
  for (int j = 0; j < DDIM / 64; ++j) {
    int d = j * 64 + lane;
    float xv = xr[d];
    const float4* w = (const float4*)(rw + d * NEXP);
    float4 w0 = w[0], w1 = w[1];
    acc[0] += xv * w0.x; acc[1] += xv * w0.y; acc[2] += xv * w0.z; acc[3] += xv * w0.w;
    acc[4] += xv * w1.x; acc[5] += xv * w1.y; acc[6] += xv * w1.z; acc[7] += xv * w1.w;
  }
#pragma unroll
  for (int e = 0; e < NEXP; ++e) {
    float v = acc[e];
    for (int off = 32; off > 0; off >>= 1) v += __shfl_xor(v, off, 64);
    acc[e] = v;
  }
  if (lane == 0) {
    float l[NEXP];
#pragma unroll
    for (int e = 0; e < NEXP; ++e) l[e] = acc[e] + rb[e];
    int i0 = 0; float b0 = l[0];
#pragma unroll
    for (int e = 1; e < NEXP; ++e) if (l[e] > b0) { b0 = l[e]; i0 = e; }
    int i1 = -1; float b1 = -3.0e38f;
#pragma unroll
    for (int e = 0; e < NEXP; ++e) if (e != i0 && l[e] > b1) { b1 = l[e]; i1 = e; }
    float e1 = expf(b1 - b0);
    float inv = 1.f / (1.f + e1);
    wts[token * 2 + 0] = inv;
    wts[token * 2 + 1] = e1 * inv;
    pexp[token * 2 + 0] = i0;
    pexp[token * 2 + 1] = i1;
    int s0 = atomicAdd(&cnt[i0], 1);
    lists[i0 * T_TOK + s0] = token * 2;
    int s1 = atomicAdd(&cnt[i1], 1);
    lists[i1 * T_TOK + s1] = token * 2 + 1;
  }
}

// ---------------- GEMM1: fused gate/up, R2-proven structure, 128x128 tile, BK=64 ----------------
__global__ __launch_bounds__(256, 2) void gemm1_kernel(
    const ushort* __restrict__ xb, const ushort* __restrict__ wcat,
    const float* __restrict__ gate_b, const float* __restrict__ up_b,
    const int* __restrict__ lists, const int* __restrict__ cnt,
    ushort* __restrict__ hbuf) {
  const int e = blockIdx.z;
  const int ce = cnt[e];
  const int m0 = blockIdx.x * 128;
  if (m0 >= ce) return;
  const int by = blockIdx.y;  // 0..31 -> cols 64*by..+63 (gate & up)

  __shared__ __align__(16) ushort smem[2 * 128 * 64];  // As | Bs, 32 KB
  __shared__ int rowinfo[128];
  ushort* As = smem;
  ushort* Bs = smem + 128 * 64;

  const int tid = threadIdx.x;
  if (tid < 128) {
    int slot = m0 + tid;
    rowinfo[tid] = lists[e * T_TOK + (slot < ce ? slot : 0)];
  }
  __syncthreads();

  const int w = tid >> 6, lane = tid & 63;
  const int fm = lane & 15, fq = lane >> 4;
  const int waveM = w >> 1, waveN = w & 1;
  const int lr = lane >> 3;
  const int lchunk = ((lane & 7) ^ lr) * 8;

  const ushort* wcatE = wcat + (size_t)e * 4096 * 1024;
  const ushort* aG[4]; const ushort* bG[4];
  ushort* aL[4]; ushort* bL[4];
#pragma unroll
  for (int j = 0; j < 4; ++j) {
    int rl = 32 * w + 8 * j + lr;
    aG[j] = xb + (size_t)(rowinfo[rl] >> 1) * DDIM + lchunk;
    bG[j] = wcatE + (size_t)(128 * by + rl) * DDIM + lchunk;
    aL[j] = As + (32 * w + 8 * j) * 64;
    bL[j] = Bs + (32 * w + 8 * j) * 64;
  }

  f32x4 acc[4][4];
  const f32x4 zero4 = {0.f, 0.f, 0.f, 0.f};
#pragma unroll
  for (int i = 0; i < 4; ++i)
#pragma unroll
    for (int j = 0; j < 4; ++j) acc[i][j] = zero4;

#pragma unroll 1
  for (int kt = 0; kt < DDIM / 64; ++kt) {
    __syncthreads();
#pragma unroll
    for (int j = 0; j < 4; ++j) {
      async_copy16(aL[j], aG[j] + kt * 64);
      async_copy16(bL[j], bG[j] + kt * 64);
    }
    __syncthreads();
#pragma unroll
    for (int ks = 0; ks < 2; ++ks) {
      bf16x8 af[4], bfr[4];
#pragma unroll
      for (int mf = 0; mf < 4; ++mf) {
        int row = 64 * waveM + 16 * mf + fm;
        af[mf] = *(const bf16x8*)&As[row * 64 + (((ks * 4 + fq) ^ (fm & 7)) * 8)];
      }
#pragma unroll
      for (int nf = 0; nf < 4; ++nf) {
        int row = 64 * waveN + 16 * nf + fm;
        bfr[nf] = *(const bf16x8*)&Bs[row * 64 + (((ks * 4 + fq) ^ (fm & 7)) * 8)];
      }
#pragma unroll
      for (int mf = 0; mf < 4; ++mf)
#pragma unroll
        for (int nf = 0; nf < 4; ++nf)
          acc[mf][nf] = __builtin_amdgcn_mfma_f32_16x16x32_bf16(af[mf], bfr[nf], acc[mf][nf], 0, 0, 0);
    }
  }

  // epilogue: up-waves publish u via LDS; gate-waves fuse silu(g)*u
  __syncthreads();
  float* uld = (float*)smem;  // [128][64] fp32 = 32 KB
  if (waveN == 1) {
#pragma unroll
    for (int mf = 0; mf < 4; ++mf)
#pragma unroll
      for (int nf = 0; nf < 4; ++nf)
#pragma unroll
        for (int r = 0; r < 4; ++r)
          uld[(64 * waveM + 16 * mf + 4 * fq + r) * 64 + 16 * nf + fm] = acc[mf][nf][r];
  }
  __syncthreads();
  if (waveN == 0) {
#pragma unroll
    for (int mf = 0; mf < 4; ++mf) {
#pragma unroll
      for (int r = 0; r < 4; ++r) {
        const int row = 64 * waveM + 16 * mf + 4 * fq + r;
        if (m0 + row < ce) {
          const int packed = rowinfo[row];
#pragma unroll
          for (int nf = 0; nf < 4; ++nf) {
            const int col = 64 * by + 16 * nf + fm;
            float g = acc[mf][nf][r] + gate_b[e * IDIM + col];
            float u = uld[row * 64 + 16 * nf + fm] + up_b[e * IDIM + col];
            float h = g * (1.f / (1.f + __expf(-g))) * u;
            hbuf[(size_t)packed * IDIM + col] = f2bf(h);
          }
        }
      }
    }
  }
}

// ---------------- GEMM2: cbuf[pair] = h @ down_w (no bias, no weight, NO atomics) ----------------
__global__ __launch_bounds__(256, 2) void gemm2_kernel(
    const ushort* __restrict__ hbuf, const ushort* __restrict__ downT,
    const int* __restrict__ lists, const int* __restrict__ cnt,
    ushort* __restrict__ cbuf) {
  const int e = blockIdx.z;
  const int ce = cnt[e];
  const int m0 = blockIdx.x * 128;
  if (m0 >= ce) return;
  const int by = blockIdx.y;  // 0..7 -> cols 128*by..

  __shared__ __align__(16) ushort smem[2 * 128 * 64];
  __shared__ int rowinfo[128];
  ushort* As = smem;
  ushort* Bs = smem + 128 * 64;

  const int tid = threadIdx.x;
  if (tid < 128) {
    int slot = m0 + tid;
    rowinfo[tid] = lists[e * T_TOK + (slot < ce ? slot : 0)];
  }
  __syncthreads();

  const int w = tid >> 6, lane = tid & 63;
  const int fm = lane & 15, fq = lane >> 4;
  const int waveM = w >> 1, waveN = w & 1;
  const int lr = lane >> 3;
  const int lchunk = ((lane & 7) ^ lr) * 8;

  const ushort* downE = downT + (size_t)e * DDIM * IDIM;
  const ushort* aG[4]; const ushort* bG[4];
  ushort* aL[4]; ushort* bL[4];
#pragma unroll
  for (int j = 0; j < 4; ++j) {
    int rl = 32 * w + 8 * j + lr;
    aG[j] = hbuf + (size_t)rowinfo[rl] * IDIM + lchunk;
    bG[j] = downE + (size_t)(128 * by + rl) * IDIM + lchunk;
    aL[j] = As + (32 * w + 8 * j) * 64;
    bL[j] = Bs + (32 * w + 8 * j) * 64;
  }

  f32x4 acc[4][4];
  const f32x4 zero4 = {0.f, 0.f, 0.f, 0.f};
#pragma unroll
  for (int i = 0; i < 4; ++i)
#pragma unroll
    for (int j = 0; j < 4; ++j) acc[i][j] = zero4;

#pragma unroll 1
  for (int kt = 0; kt < IDIM / 64; ++kt) {
    __syncthreads();
#pragma unroll
    for (int j = 0; j < 4; ++j) {
      async_copy16(aL[j], aG[j] + kt * 64);
      async_copy16(bL[j], bG[j] + kt * 64);
    }
    __syncthreads();
#pragma unroll
    for (int ks = 0; ks < 2; ++ks) {
      bf16x8 af[4], bfr[4];
#pragma unroll
      for (int mf = 0; mf < 4; ++mf) {
        int row = 64 * waveM + 16 * mf + fm;
        af[mf] = *(const bf16x8*)&As[row * 64 + (((ks * 4 + fq) ^ (fm & 7)) * 8)];
      }
#pragma unroll
      for (int nf = 0; nf < 4; ++nf) {
        int row = 64 * waveN + 16 * nf + fm;
        bfr[nf] = *(const bf16x8*)&Bs[row * 64 + (((ks * 4 + fq) ^ (fm & 7)) * 8)];
      }
#pragma unroll
      for (int mf = 0; mf < 4; ++mf)
#pragma unroll
        for (int nf = 0; nf < 4; ++nf)
          acc[mf][nf] = __builtin_amdgcn_mfma_f32_16x16x32_bf16(af[mf], bfr[nf], acc[mf][nf], 0, 0, 0);
    }
  }

#pragma unroll
  for (int mf = 0; mf < 4; ++mf) {
#pragma unroll
    for (int r = 0; r < 4; ++r) {
      const int row = 64 * waveM + 16 * mf + 4 * fq + r;
      if (m0 + row < ce) {
        const int packed = rowinfo[row];
        ushort* crow = cbuf + (size_t)packed * DDIM + 128 * by + 64 * waveN;
#pragma unroll
        for (int nf = 0; nf < 4; ++nf)
          crow[16 * nf + fm] = f2bf(acc[mf][nf][r]);
      }
    }
  }
}

// ---------------- combine: out[t] = w0*(c0+db[e0]) + w1*(c1+db[e1]) ----------------
__global__ __launch_bounds__(256) void combine_kernel(
    const ushort* __restrict__ cbuf, const float* __restrict__ down_b,
    const int* __restrict__ pexp, const float* __restrict__ wts,
    float* __restrict__ out) {
  const int i = blockIdx.x * 256 + threadIdx.x;  // one thread per 8 cols
  const int token = i >> 7;                      // DDIM/8 = 128 segs
  const int seg = (i & 127) * 8;
  const float w0 = wts[token * 2], w1 = wts[token * 2 + 1];
  const int e0 = pexp[token * 2], e1 = pexp[token * 2 + 1];
  const ushort* c0 = cbuf + (size_t)(token * 2) * DDIM + seg;
  const ushort* c1 = c0 + DDIM;
  const float* b0 = down_b + e0 * DDIM + seg;
  const float* b1 = down_b + e1 * DDIM + seg;
  ushort4 v0a = ((const ushort4*)c0)[0], v0b = ((const ushort4*)c0)[1];
  ushort4 v1a = ((const ushort4*)c1)[0], v1b = ((const ushort4*)c1)[1];
  float4 ba0 = ((const float4*)b0)[0], bb0 = ((const float4*)b0)[1];
  float4 ba1 = ((const float4*)b1)[0], bb1 = ((const float4*)b1)[1];
  float4 o0, o1;
  o0.x = w0 * (bf2f(v0a.x) + ba0.x) + w1 * (bf2f(v1a.x) + ba1.x);
  o0.y = w0 * (bf2f(v0a.y) + ba0.y) + w1 * (bf2f(v1a.y) + ba1.y);
  o0.z = w0 * (bf2f(v0a.z) + ba0.z) + w1 * (bf2f(v1a.z) + ba1.z);
  o0.w = w0 * (bf2f(v0a.w) + ba0.w) + w1 * (bf2f(v1a.w) + ba1.w);
  o1.x = w0 * (bf2f(v0b.x) + bb0.x) + w1 * (bf2f(v1b.x) + bb1.x);
  o1.y = w0 * (bf2f(v0b.y) + bb0.y) + w1 * (bf2f(v1b.y) + bb1.y);
  o1.z = w0 * (bf2f(v0b.z) + bb0.z) + w1 * (bf2f(v1b.z) + bb1.z);
  o1.w = w0 * (bf2f(v0b.w) + bb0.w) + w1 * (bf2f(v1b.w) + bb1.w);
  float* op = out + (size_t)token * DDIM + seg;
  ((float4*)op)[0] = o0;
  ((float4*)op)[1] = o1;
}

extern "C" void kernel_launch(void* const* d_in, const int* in_sizes, int n_in,
                              void* d_out, int out_size, void* d_ws, size_t ws_size,
                              hipStream_t stream) {
  const float* x = (const float*)d_in[0];
  const float* rw = (const float*)d_in[1];
  const float* rb = (const float*)d_in[2];
  const float* gw = (const float*)d_in[3];
  const float* gb = (const float*)d_in[4];
  const float* uw = (const float*)d_in[5];
  const float* ub = (const float*)d_in[6];
  const float* dw = (const float*)d_in[7];
  const float* db = (const float*)d_in[8];
  float* out = (float*)d_out;

  char* ws = (char*)d_ws;
  ushort* xb    = (ushort*)(ws);                              // 16 MB
  ushort* hbuf  = (ushort*)(ws + (16ull << 20));              // 64 MB
  ushort* wcat  = (ushort*)(ws + (80ull << 20));              // 64 MB (dead after gemm1)
  ushort* cbuf  = wcat;                                       // 32 MB, aliases wcat
  ushort* downT = (ushort*)(ws + (144ull << 20));             // 32 MB
  float*  wts   = (float*) (ws + (176ull << 20));             // 64 KB
  int*    lists = (int*)   (ws + (176ull << 20) + 65536);     // 256 KB
  int*    cnt   = (int*)   (ws + (176ull << 20) + 65536 + 262144);
  int*    pexp  = (int*)   (ws + (176ull << 20) + 65536 + 262144 + 4096);  // 64 KB

  hipMemsetAsync(cnt, 0, NEXP * sizeof(int), stream);

  convert_kernel<<<(T_TOK * DDIM / 4 + 255) / 256, 256, 0, stream>>>(x, xb, T_TOK * DDIM / 4);
  router_kernel<<<T_TOK / 4, 256, 0, stream>>>(x, rw, rb, cnt, lists, wts, pexp);
  tconv_kernel<<<dim3(IDIM / 64, DDIM / 64, NEXP), 256, 0, stream>>>(
      gw, wcat, DDIM, IDIM, 0, 1, (size_t)DDIM * IDIM, (size_t)2 * IDIM * DDIM);
  tconv_kernel<<<dim3(IDIM / 64, DDIM / 64, NEXP), 256, 0, stream>>>(
      uw, wcat, DDIM, IDIM, 1, 1, (size_t)DDIM * IDIM, (size_t)2 * IDIM * DDIM);
  tconv_kernel<<<dim3(DDIM / 64, IDIM / 64, NEXP), 256, 0, stream>>>(
      dw, downT, IDIM, DDIM, 0, 0, (size_t)IDIM * DDIM, (size_t)DDIM * IDIM);

  gemm1_kernel<<<dim3(T_TOK / 128, IDIM / 64, NEXP), 256, 0, stream>>>(
      xb, wcat, gb, ub, lists, cnt, hbuf);
  gemm2_kernel<<<dim3(T_TOK / 128, DDIM / 128, NEXP), 256, 0, stream>>>(
      hbuf, downT, lists, cnt, cbuf);
  combine_kernel<<<T_TOK * DDIM / 8 / 256, 256, 0, stream>>>(cbuf, db, pexp, wts, out);
}